// Round 4
// baseline (8502.919 us; speedup 1.0000x reference)
//
#include <hip/hip_runtime.h>

typedef unsigned int u32;
typedef _Float16 h1;
typedef _Float16 h2 __attribute__((ext_vector_type(2)));

// Problem dims: B=512, T-1=63, N=512, H=256, 4H=1024

#define OFF_IE (512*63*512)
#define OFF_W  (512*63*512 + 512*63*256)

// C2 = 2*log2(e): tanh(x) = 1 - 2/(1 + exp2(C2*x)).
// Wc, bc, t2 are pre-scaled by C2 so phase 2 does exp2(t1c + t2c) directly.
#define C2 2.885390081777927f

// Workspace layout (bytes):
//   t2 half [512][63][512] (pre-scaled) @ 0          (33,030,144)
//   WihP u32 [256 n2][1024 k]           @ 33,030,144 (1,048,576)
//   WhhP u32 [128 j2][1024 k]           @ 34,078,720 (  524,288)
//   WcH  half [63][512]  (x C2)        @ 34,603,008 (   64,512)
//   bias f32 [1024]                    @ 34,667,520 (    4,096)

__device__ __forceinline__ float tanh_fast(float x){
    float e = __builtin_amdgcn_exp2f(x * C2);
    return 1.0f - 2.0f * __builtin_amdgcn_rcpf(e + 1.0f);
}
__device__ __forceinline__ float sigmoid_fast(float x){
    float e = __builtin_amdgcn_exp2f(x * -1.4426950408889634f);
    return __builtin_amdgcn_rcpf(1.0f + e);
}
__device__ __forceinline__ float exp_fast(float x){
    return __builtin_amdgcn_exp2f(x * 1.4426950408889634f);
}
__device__ __forceinline__ float dot2h(u32 a, u32 w, float c){
    return __builtin_amdgcn_fdot2(__builtin_bit_cast(h2, a),
                                  __builtin_bit_cast(h2, w), c, false);
}

// Barrier that waits only on LDS ops (lgkmcnt) and leaves global loads in
// flight (no vmcnt(0) drain). Safe here: no global RAW hazards exist inside
// encoder_main (weights/inp/t2 are read-only; out is never read back).
__device__ __forceinline__ void bar_lgkm(){
    asm volatile("s_waitcnt lgkmcnt(0)" ::: "memory");
    __builtin_amdgcn_s_barrier();
    asm volatile("" ::: "memory");
}

__global__ __launch_bounds__(256)
void prep_pack(const float* __restrict__ Wih, const float* __restrict__ Whh,
               const float* __restrict__ bih, const float* __restrict__ bhh,
               const float* __restrict__ Wc,
               u32* __restrict__ WihP, u32* __restrict__ WhhP,
               h1* __restrict__ WcH, float* __restrict__ biasg)
{
    int i = blockIdx.x*256 + threadIdx.x;
    if (i < 262144){                       // W_ih [1024][512] -> [n2][k] half2
        int k = i >> 8, n2 = i & 255;
        float2 w = *(const float2*)(Wih + (size_t)k*512 + 2*n2);
        h2 p; p[0] = (h1)w.x; p[1] = (h1)w.y;
        WihP[n2*1024 + k] = __builtin_bit_cast(u32, p);
    } else if (i < 393216){                // W_hh [1024][256] -> [j2][k] half2
        int j = i - 262144;
        int k = j >> 7, j2 = j & 127;
        float2 w = *(const float2*)(Whh + (size_t)k*256 + 2*j2);
        h2 p; p[0] = (h1)w.x; p[1] = (h1)w.y;
        WhhP[j2*1024 + k] = __builtin_bit_cast(u32, p);
    } else if (i < 425472){                // Wc -> half, scaled by C2
        int j = i - 393216;
        WcH[j] = (h1)(C2 * Wc[j]);
    } else if (i < 426496){                // bias = b_ih + b_hh
        int k = i - 425472;
        biasg[k] = bih[k] + bhh[k];
    }
}

__global__ __launch_bounds__(256)
void prep_t2(const float* __restrict__ inp, const float* __restrict__ Wd,
             const float* __restrict__ bd, h1* __restrict__ t2)
{
    __shared__ float wd_s[63*63];
    __shared__ float bd_s[63];
    int tid = threadIdx.x;
    for (int i = tid; i < 3969; i += 256) wd_s[i] = Wd[i];
    if (tid < 63) bd_s[tid] = bd[tid];
    __syncthreads();
    int bb = blockIdx.x;                 // batch
    int n  = blockIdx.y*256 + tid;       // input-feature
    float x[63];
    const float* ip = inp + (size_t)bb*63*512 + n;
    #pragma unroll
    for (int t = 0; t < 63; ++t) x[t] = ip[(size_t)t*512];
    h1* op = t2 + (size_t)bb*63*512 + n;
    for (int s = 0; s < 63; ++s){
        float acc = bd_s[s];
        const float* w = wd_s + s*63;
        #pragma unroll
        for (int t = 0; t < 63; ++t) acc = fmaf(x[t], w[t], acc);
        op[(size_t)s*512] = (h1)(C2 * acc);   // single rounding, pre-scaled
    }
}

// 8 dot2 per weight-row: 4 gate-quads x 2 batches.
#define DOTQ8(X0, X1, W) \
    a0 = dot2h((X0), (W).x, a0); a1 = dot2h((X0), (W).y, a1); \
    a2 = dot2h((X0), (W).z, a2); a3 = dot2h((X0), (W).w, a3); \
    b0 = dot2h((X1), (W).x, b0); b1 = dot2h((X1), (W).y, b1); \
    b2 = dot2h((X1), (W).z, b2); b3 = dot2h((X1), (W).w, b3);

// Load one 8-row block (this thread's k-quad column) as 8 dwordx4.
#define PRE8Q(BUF, PTR) { const uint4* _pp = (PTR); \
    _Pragma("unroll") for (int _u = 0; _u < 8; ++_u) BUF[_u] = _pp[_u*256]; }

// Consume one 8-row block against both batches' packed x vectors.
#define CONSUME8Q(BUF, XS0, XS1, J0) { \
    uint4 _x0 = *(const uint4*)&(XS0)[(J0)];   uint4 _x1 = *(const uint4*)&(XS0)[(J0)+4]; \
    uint4 _y0 = *(const uint4*)&(XS1)[(J0)];   uint4 _y1 = *(const uint4*)&(XS1)[(J0)+4]; \
    DOTQ8(_x0.x,_y0.x,BUF[0]) DOTQ8(_x0.y,_y0.y,BUF[1]) \
    DOTQ8(_x0.z,_y0.z,BUF[2]) DOTQ8(_x0.w,_y0.w,BUF[3]) \
    DOTQ8(_x1.x,_y1.x,BUF[4]) DOTQ8(_x1.y,_y1.y,BUF[5]) \
    DOTQ8(_x1.z,_y1.z,BUF[6]) DOTQ8(_x1.w,_y1.w,BUF[7]) }

// One attention-score iteration (2 s-values for this thread's 2 n's).
// Uses locals: trow, t1r, acc0, acc1.
#define P2_ITER(Q) { \
    uint2 tv = *(const uint2*)(trow + 2*(Q)); \
    float2 t1v = *(const float2*)&t1r[2*(Q)]; \
    float2 wv  = *(const float2*)&wamL[2*(Q)]; \
    h2 va = __builtin_bit_cast(h2, tv.x); \
    h2 vb = __builtin_bit_cast(h2, tv.y); \
    float r0 = __builtin_amdgcn_rcpf(1.f + __builtin_amdgcn_exp2f(t1v.x + (float)va[0])); \
    float r1 = __builtin_amdgcn_rcpf(1.f + __builtin_amdgcn_exp2f(t1v.x + (float)va[1])); \
    float r2 = __builtin_amdgcn_rcpf(1.f + __builtin_amdgcn_exp2f(t1v.y + (float)vb[0])); \
    float r3 = __builtin_amdgcn_rcpf(1.f + __builtin_amdgcn_exp2f(t1v.y + (float)vb[1])); \
    acc0 = fmaf(wv.x, r0, acc0); \
    acc1 = fmaf(wv.x, r1, acc1); \
    acc0 = fmaf(wv.y, r2, acc0); \
    acc1 = fmaf(wv.y, r3, acc1); }

// R3 structure (512 thr, 1 WG/CU, 1910us verified) + this round's change:
// dwordx4 weight stream with a shared 4-buffer rotation.
//  - thread t<256 owns gate-quad k=4t..4t+3; tid>=256 same quads, other
//    input-row half. Partial gates summed via gU in phase 4.
//  - Same bytes, HALF the VMEM instructions, 1KB/instr coalescing, and
//    32 dwordx4 (512B/thread) in flight vs R3's 16 dwordx2 (128B).
//  - VGPR budget: 2 waves/SIMD -> 256/wave; buffers use 128. R1/R2 spills
//    came from 1024-thread configs' 128-VGPR cap. WRITE_SIZE==161,280KB
//    is the no-spill canary.
__global__ __launch_bounds__(512, 2)
void encoder_main(const float* __restrict__ inp, const float* __restrict__ bc,
                  const float* __restrict__ Wa, const float* __restrict__ ba,
                  const h1* __restrict__ t2g, const u32* __restrict__ WihP,
                  const u32* __restrict__ WhhP, const h1* __restrict__ WcH,
                  const float* __restrict__ biasg, float* __restrict__ out)
{
    // LDS: 135168 + 2048 + 2048 + 512 + 2016 + 16384 + 32 + 256 = 158,464 B
    __shared__ u32   t2l[2][256][66];   // row = (b,n2), word s (stride 66 for banks)
    __shared__ u32   hcp[2][256];       // [0..127]=h packed h2, [128..255]=c packed h2
    __shared__ u32   wxp[2][256];       // wx packed h2
    __shared__ float t1s[2][64];        // t1 (scaled); [63] stays 0
    __shared__ float t1p[126][4];
    __shared__ float gU[2][2][1024];    // gate partials [row-half][batch][k]
    __shared__ float red[8];
    __shared__ float wamL[64];          // -2*Wa[s]; [63]=0

    const int tid  = threadIdx.x;
    const int wg   = blockIdx.x;         // 0..255, owns batches 2wg, 2wg+1
    const int n2   = tid & 255;          // n2 for P2/P4; gate-quad for streams
    const int b    = tid >> 8;           // batch for P2/P4
    const int half = tid >> 8;           // input-row half for weight streams
    const int bG   = wg*2 + b;

    // ---- prologue ----
    hcp[b][n2] = 0u;                     // h=c=0
    if (tid < 64) wamL[tid] = (tid < 63) ? (-2.0f * Wa[tid]) : 0.0f;
    if (tid < 128) ((float*)t1s)[tid] = 0.0f;
    float4 bi4 = make_float4(0.f, 0.f, 0.f, 0.f);   // bias once (half 0 only)
    if (half == 0) bi4 = *(const float4*)&biasg[4*n2];
    float bcv = 0.0f;
    if (tid < 126){
        int pb = (tid >= 63) ? 1 : 0;
        bcv = C2 * bc[tid - 63*pb];
    }
    // stage t2 (pre-scaled h2 pairs) into LDS, transposed to [b][n2][s]
    {
        const u32* tg = (const u32*)(t2g + (size_t)bG*63*512);
        u32* trw = &t2l[b][n2][0];
        for (int s = 0; s < 63; ++s) trw[s] = tg[s*256 + n2];
        trw[63] = 0u; trw[64] = 0u; trw[65] = 0u;
    }
    float c_reg = 0.0f;                 // this thread's fp32 cell state (j = n2, batch b)
    // dwordx4 stream bases: column = gate-quad n2, rows = this half's rows.
    const uint4* ihb = (const uint4*)WihP + (size_t)(half*128)*256 + n2;
    const uint4* hhb = (const uint4*)WhhP + (size_t)(half*64)*256 + n2;
    const int HJ = half*64;              // hcp row base for hh consume
    __syncthreads();

    uint4 B0[8], B1[8], B2[8], B3[8];

    for (int t = 0; t < 63; ++t){
        // step prologue: x-vector + first 4 W_hh blocks in flight across
        // phase 1 and both lgkm-only barriers.
        float2 xv = *(const float2*)(inp + ((size_t)bG*63 + t)*512 + 2*n2);
        PRE8Q(B0, hhb)
        PRE8Q(B1, hhb + 2048)
        PRE8Q(B2, hhb + 2*2048)
        PRE8Q(B3, hhb + 3*2048)

        // ---------- phase 1: t1[b][s] = C2*([h|c].Wc[s] + bc[s])  (fp16 dot2)
        if (tid < 504){
            int oi = tid >> 2, sl = tid & 3;
            int pb = (oi >= 63) ? 1 : 0;
            int s  = oi - 63*pb;
            const uint4* xv4 = (const uint4*)&hcp[pb][sl*64];
            const uint4* wv4 = (const uint4*)(WcH + s*512 + sl*128);
            float acc = 0.f;
            #pragma unroll
            for (int i = 0; i < 16; ++i){
                uint4 x = xv4[i], w = wv4[i];
                acc = dot2h(x.x, w.x, acc);
                acc = dot2h(x.y, w.y, acc);
                acc = dot2h(x.z, w.z, acc);
                acc = dot2h(x.w, w.w, acc);
            }
            t1p[oi][sl] = acc;
        }
        bar_lgkm();
        if (tid < 126){
            int pb = (tid >= 63) ? 1 : 0;
            int s  = tid - 63*pb;
            float4 v = *(const float4*)&t1p[tid][0];
            t1s[pb][s] = bcv + v.x + v.y + v.z + v.w;
        }
        bar_lgkm();

        // ---------- phase 2: scores interleaved with the W_hh stream
        //            (8 blocks/thread; W_hh needs only h(t-1) = hcp)
        float acc0 = 0.f, acc1 = 0.f;
        float a0 = bi4.x, a1 = bi4.y, a2 = bi4.z, a3 = bi4.w;
        float b0 = bi4.x, b1 = bi4.y, b2 = bi4.z, b3 = bi4.w;
        const u32*   trow = &t2l[b][n2][0];
        const float* t1r  = &t1s[b][0];
        {
            P2_ITER(0)  P2_ITER(1)
            CONSUME8Q(B0, hcp[0], hcp[1], HJ+0)
            PRE8Q(B0, hhb + 4*2048)
            P2_ITER(2)  P2_ITER(3)
            P2_ITER(4)  P2_ITER(5)
            CONSUME8Q(B1, hcp[0], hcp[1], HJ+8)
            PRE8Q(B1, hhb + 5*2048)
            P2_ITER(6)  P2_ITER(7)
            P2_ITER(8)  P2_ITER(9)
            CONSUME8Q(B2, hcp[0], hcp[1], HJ+16)
            PRE8Q(B2, hhb + 6*2048)
            P2_ITER(10) P2_ITER(11)
            P2_ITER(12) P2_ITER(13)
            CONSUME8Q(B3, hcp[0], hcp[1], HJ+24)
            PRE8Q(B3, hhb + 7*2048)
            P2_ITER(14) P2_ITER(15)
            P2_ITER(16) P2_ITER(17)
            CONSUME8Q(B0, hcp[0], hcp[1], HJ+32)
            PRE8Q(B0, ihb)                   // W_ih blocks 0..3 ride across
            P2_ITER(18) P2_ITER(19)          // softmax + 2 barriers
            P2_ITER(20) P2_ITER(21)
            CONSUME8Q(B1, hcp[0], hcp[1], HJ+40)
            PRE8Q(B1, ihb + 2048)
            P2_ITER(22) P2_ITER(23)
            P2_ITER(24) P2_ITER(25)
            CONSUME8Q(B2, hcp[0], hcp[1], HJ+48)
            PRE8Q(B2, ihb + 2*2048)
            P2_ITER(26) P2_ITER(27)
            P2_ITER(28) P2_ITER(29)
            CONSUME8Q(B3, hcp[0], hcp[1], HJ+56)
            PRE8Q(B3, ihb + 3*2048)
            P2_ITER(30) P2_ITER(31)
        }
        // scores shifted by a batch-constant (dropped Swa) — softmax invariant
        float e0 = exp_fast(acc0);
        float e1 = exp_fast(acc1);
        float es = e0 + e1;
        #pragma unroll
        for (int off = 32; off > 0; off >>= 1) es += __shfl_xor(es, off, 64);
        if ((tid & 63) == 0) red[tid >> 6] = es;
        bar_lgkm();
        float tot  = red[b*4+0] + red[b*4+1] + red[b*4+2] + red[b*4+3];
        float rinv = __builtin_amdgcn_rcpf(tot);
        float at0 = e0*rinv, at1 = e1*rinv;
        float wx0 = at0*xv.x, wx1 = at1*xv.y;
        {
            float2* po = (float2*)(out + ((size_t)bG*63 + t)*512) + n2;
            *po = make_float2(wx0, wx1);
            float2* pa = (float2*)(out + OFF_W + ((size_t)bG*63 + t)*512) + n2;
            *pa = make_float2(at0, at1);
            h2 p; p[0] = (h1)wx0; p[1] = (h1)wx1;
            wxp[b][n2] = __builtin_bit_cast(u32, p);
        }
        bar_lgkm();                          // wxp visible; vmcnt NOT drained

        // ---------- phase 3: gates += wx.W_ih^T (16 blocks/thread, 4-buffer)
        #pragma unroll 1
        for (int g = 0; g < 3; ++g){
            int J = half*128 + 32*g;
            const uint4* pb4 = ihb + (4*g + 4)*2048;
            CONSUME8Q(B0, wxp[0], wxp[1], J+0)
            PRE8Q(B0, pb4)
            CONSUME8Q(B1, wxp[0], wxp[1], J+8)
            PRE8Q(B1, pb4 + 2048)
            CONSUME8Q(B2, wxp[0], wxp[1], J+16)
            PRE8Q(B2, pb4 + 2*2048)
            CONSUME8Q(B3, wxp[0], wxp[1], J+24)
            PRE8Q(B3, pb4 + 3*2048)
        }
        {   // tail: blocks 12..15, no prefetch
            int J = half*128 + 96;
            CONSUME8Q(B0, wxp[0], wxp[1], J+0)
            CONSUME8Q(B1, wxp[0], wxp[1], J+8)
            CONSUME8Q(B2, wxp[0], wxp[1], J+16)
            CONSUME8Q(B3, wxp[0], wxp[1], J+24)
        }
        *(float4*)&gU[half][0][4*n2] = make_float4(a0, a1, a2, a3);
        *(float4*)&gU[half][1][4*n2] = make_float4(b0, b1, b2, b3);
        bar_lgkm();

        // ---------- phase 4: LSTM pointwise (thread: j = n2, batch b)
        {
            int j = n2;
            float gi = gU[0][b][j]     + gU[1][b][j];
            float gf = gU[0][b][j+256] + gU[1][b][j+256];
            float gg = gU[0][b][j+512] + gU[1][b][j+512];
            float go = gU[0][b][j+768] + gU[1][b][j+768];
            float iv = sigmoid_fast(gi), fv = sigmoid_fast(gf);
            float gv = tanh_fast(gg),    ov = sigmoid_fast(go);
            float cn = fmaf(fv, c_reg, iv*gv);
            c_reg = cn;
            float hn = ov * tanh_fast(cn);
            ((h1*)&hcp[b][0])[j]   = (h1)hn;   // h packed (phase 1 + W_hh)
            ((h1*)&hcp[b][128])[j] = (h1)cn;   // c packed (phase 1)
            out[OFF_IE + ((size_t)bG*63 + t)*256 + j] = hn;
        }
        bar_lgkm();
    }
}

extern "C" void kernel_launch(void* const* d_in, const int* in_sizes, int n_in,
                              void* d_out, int out_size, void* d_ws, size_t ws_size,
                              hipStream_t stream)
{
    const float* inp = (const float*)d_in[0];
    const float* Wih = (const float*)d_in[1];
    const float* Whh = (const float*)d_in[2];
    const float* bih = (const float*)d_in[3];
    const float* bhh = (const float*)d_in[4];
    const float* Wc  = (const float*)d_in[5];
    const float* bc  = (const float*)d_in[6];
    const float* Wd  = (const float*)d_in[7];
    const float* bd  = (const float*)d_in[8];
    const float* Wa  = (const float*)d_in[9];
    const float* ba  = (const float*)d_in[10];
    float* out = (float*)d_out;

    char* ws = (char*)d_ws;
    h1*    t2    = (h1*)ws;
    u32*   WihP  = (u32*)(ws + 33030144);
    u32*   WhhP  = (u32*)(ws + 34078720);
    h1*    WcH   = (h1*)(ws + 34603008);
    float* biasg = (float*)(ws + 34667520);

    prep_pack<<<1666, 256, 0, stream>>>(Wih, Whh, bih, bhh, Wc, WihP, WhhP, WcH, biasg);
    prep_t2<<<dim3(512, 2), 256, 0, stream>>>(inp, Wd, bd, t2);
    encoder_main<<<256, 512, 0, stream>>>(inp, bc, Wa, ba, t2, WihP, WhhP, WcH, biasg, out);
}

// Round 6
// 5711.542 us; speedup vs baseline: 1.4887x; 1.4887x over previous
//
#include <hip/hip_runtime.h>

typedef unsigned int u32;
typedef _Float16 h1;
typedef _Float16 h2 __attribute__((ext_vector_type(2)));

// Problem dims: B=512, T-1=63, N=512, H=256, 4H=1024

#define OFF_IE (512*63*512)
#define OFF_W  (512*63*512 + 512*63*256)

// C2 = 2*log2(e): tanh(x) = 1 - 2/(1 + exp2(C2*x)).
// Wc, bc, t2 are pre-scaled by C2 so phase 2 does exp2(t1c + t2c) directly.
#define C2 2.885390081777927f

// Workspace layout (bytes):
//   t2 half [512][63][512] (pre-scaled) @ 0          (33,030,144)
//   WihP u32 [256 n2][1024 k]           @ 33,030,144 (1,048,576)
//   WhhP u32 [128 j2][1024 k]           @ 34,078,720 (  524,288)
//   WcH  half [63][512]  (x C2)        @ 34,603,008 (   64,512)
//   bias f32 [1024]                    @ 34,667,520 (    4,096)

__device__ __forceinline__ float tanh_fast(float x){
    float e = __builtin_amdgcn_exp2f(x * C2);
    return 1.0f - 2.0f * __builtin_amdgcn_rcpf(e + 1.0f);
}
__device__ __forceinline__ float sigmoid_fast(float x){
    float e = __builtin_amdgcn_exp2f(x * -1.4426950408889634f);
    return __builtin_amdgcn_rcpf(1.0f + e);
}
__device__ __forceinline__ float exp_fast(float x){
    return __builtin_amdgcn_exp2f(x * 1.4426950408889634f);
}
__device__ __forceinline__ float dot2h(u32 a, u32 w, float c){
    return __builtin_amdgcn_fdot2(__builtin_bit_cast(h2, a),
                                  __builtin_bit_cast(h2, w), c, false);
}

// Barrier that waits only on LDS ops (lgkmcnt) and leaves global loads in
// flight (no vmcnt(0) drain). Safe here: no global RAW hazards exist inside
// encoder_main (weights/inp/t2 are read-only; out is never read back).
__device__ __forceinline__ void bar_lgkm(){
    asm volatile("s_waitcnt lgkmcnt(0)" ::: "memory");
    __builtin_amdgcn_s_barrier();
    asm volatile("" ::: "memory");
}

__global__ __launch_bounds__(256)
void prep_pack(const float* __restrict__ Wih, const float* __restrict__ Whh,
               const float* __restrict__ bih, const float* __restrict__ bhh,
               const float* __restrict__ Wc,
               u32* __restrict__ WihP, u32* __restrict__ WhhP,
               h1* __restrict__ WcH, float* __restrict__ biasg)
{
    int i = blockIdx.x*256 + threadIdx.x;
    if (i < 262144){                       // W_ih [1024][512] -> [n2][k] half2
        int k = i >> 8, n2 = i & 255;
        float2 w = *(const float2*)(Wih + (size_t)k*512 + 2*n2);
        h2 p; p[0] = (h1)w.x; p[1] = (h1)w.y;
        WihP[n2*1024 + k] = __builtin_bit_cast(u32, p);
    } else if (i < 393216){                // W_hh [1024][256] -> [j2][k] half2
        int j = i - 262144;
        int k = j >> 7, j2 = j & 127;
        float2 w = *(const float2*)(Whh + (size_t)k*256 + 2*j2);
        h2 p; p[0] = (h1)w.x; p[1] = (h1)w.y;
        WhhP[j2*1024 + k] = __builtin_bit_cast(u32, p);
    } else if (i < 425472){                // Wc -> half, scaled by C2
        int j = i - 393216;
        WcH[j] = (h1)(C2 * Wc[j]);
    } else if (i < 426496){                // bias = b_ih + b_hh
        int k = i - 425472;
        biasg[k] = bih[k] + bhh[k];
    }
}

__global__ __launch_bounds__(256)
void prep_t2(const float* __restrict__ inp, const float* __restrict__ Wd,
             const float* __restrict__ bd, h1* __restrict__ t2)
{
    __shared__ float wd_s[63*63];
    __shared__ float bd_s[63];
    int tid = threadIdx.x;
    for (int i = tid; i < 3969; i += 256) wd_s[i] = Wd[i];
    if (tid < 63) bd_s[tid] = bd[tid];
    __syncthreads();
    int bb = blockIdx.x;                 // batch
    int n  = blockIdx.y*256 + tid;       // input-feature
    float x[63];
    const float* ip = inp + (size_t)bb*63*512 + n;
    #pragma unroll
    for (int t = 0; t < 63; ++t) x[t] = ip[(size_t)t*512];
    h1* op = t2 + (size_t)bb*63*512 + n;
    for (int s = 0; s < 63; ++s){
        float acc = bd_s[s];
        const float* w = wd_s + s*63;
        #pragma unroll
        for (int t = 0; t < 63; ++t) acc = fmaf(x[t], w[t], acc);
        op[(size_t)s*512] = (h1)(C2 * acc);   // single rounding, pre-scaled
    }
}

// 8 dot2 per weight-row: 4 gate-quads x 2 batches.
#define DOTQ8(X0, X1, W) \
    a0 = dot2h((X0), (W).x, a0); a1 = dot2h((X0), (W).y, a1); \
    a2 = dot2h((X0), (W).z, a2); a3 = dot2h((X0), (W).w, a3); \
    b0 = dot2h((X1), (W).x, b0); b1 = dot2h((X1), (W).y, b1); \
    b2 = dot2h((X1), (W).z, b2); b3 = dot2h((X1), (W).w, b3);

// Load one 8-row block (this thread's k-quad column) as 8 dwordx4.
#define PRE8Q(BUF, PTR) { const uint4* _pp = (PTR); \
    _Pragma("unroll") for (int _u = 0; _u < 8; ++_u) BUF[_u] = _pp[_u*256]; }

// Consume one 8-row block against both batches' packed x vectors.
#define CONSUME8Q(BUF, XS0, XS1, J0) { \
    uint4 _x0 = *(const uint4*)&(XS0)[(J0)];   uint4 _x1 = *(const uint4*)&(XS0)[(J0)+4]; \
    uint4 _y0 = *(const uint4*)&(XS1)[(J0)];   uint4 _y1 = *(const uint4*)&(XS1)[(J0)+4]; \
    DOTQ8(_x0.x,_y0.x,BUF[0]) DOTQ8(_x0.y,_y0.y,BUF[1]) \
    DOTQ8(_x0.z,_y0.z,BUF[2]) DOTQ8(_x0.w,_y0.w,BUF[3]) \
    DOTQ8(_x1.x,_y1.x,BUF[4]) DOTQ8(_x1.y,_y1.y,BUF[5]) \
    DOTQ8(_x1.z,_y1.z,BUF[6]) DOTQ8(_x1.w,_y1.w,BUF[7]) }

// One attention-score iteration (2 s-values for this thread's 2 n's).
// Uses locals: trow, t1r, acc0, acc1.
#define P2_ITER(Q) { \
    uint2 tv = *(const uint2*)(trow + 2*(Q)); \
    float2 t1v = *(const float2*)&t1r[2*(Q)]; \
    float2 wv  = *(const float2*)&wamL[2*(Q)]; \
    h2 va = __builtin_bit_cast(h2, tv.x); \
    h2 vb = __builtin_bit_cast(h2, tv.y); \
    float r0 = __builtin_amdgcn_rcpf(1.f + __builtin_amdgcn_exp2f(t1v.x + (float)va[0])); \
    float r1 = __builtin_amdgcn_rcpf(1.f + __builtin_amdgcn_exp2f(t1v.x + (float)va[1])); \
    float r2 = __builtin_amdgcn_rcpf(1.f + __builtin_amdgcn_exp2f(t1v.y + (float)vb[0])); \
    float r3 = __builtin_amdgcn_rcpf(1.f + __builtin_amdgcn_exp2f(t1v.y + (float)vb[1])); \
    acc0 = fmaf(wv.x, r0, acc0); \
    acc1 = fmaf(wv.x, r1, acc1); \
    acc0 = fmaf(wv.y, r2, acc0); \
    acc1 = fmaf(wv.y, r3, acc1); }

// R3 structure (512 thr, 1 WG/CU, 1910us verified, launch_bounds(512,1))
// with the dwordx4 weight stream, retried at R3's register footprint:
//  - thread t<256 owns gate-quad k=4t..4t+3; tid>=256 same quads, other
//    input-row half. Partial gates summed via gU in phase 4.
//  - TWO uint4[8] buffers (64 buffer VGPRs, same as R3's four uint2[8]).
//    R4's four uint4 buffers + launch_bounds(512,2) imposed a 128-VGPR cap
//    (2nd arg empirically = min BLOCKS: 16 waves/CU -> 2048/16 = 128) and
//    spilled everything: WRITE 161MB->11.8GB, 8503us. NEVER use 2nd arg > 1
//    here; WRITE_SIZE==161,280KB is the no-spill canary.
//  - Same bytes as R3, HALF the VMEM instructions, 1KB/wave-instr
//    coalescing, 256B/thread in flight (2x R3).
// (R5 run of this exact source died to container infra failure; resubmit.)
__global__ __launch_bounds__(512, 1)
void encoder_main(const float* __restrict__ inp, const float* __restrict__ bc,
                  const float* __restrict__ Wa, const float* __restrict__ ba,
                  const h1* __restrict__ t2g, const u32* __restrict__ WihP,
                  const u32* __restrict__ WhhP, const h1* __restrict__ WcH,
                  const float* __restrict__ biasg, float* __restrict__ out)
{
    // LDS: 135168 + 2048 + 2048 + 512 + 2016 + 16384 + 32 + 256 = 158,464 B
    __shared__ u32   t2l[2][256][66];   // row = (b,n2), word s (stride 66 for banks)
    __shared__ u32   hcp[2][256];       // [0..127]=h packed h2, [128..255]=c packed h2
    __shared__ u32   wxp[2][256];       // wx packed h2
    __shared__ float t1s[2][64];        // t1 (scaled); [63] stays 0
    __shared__ float t1p[126][4];
    __shared__ float gU[2][2][1024];    // gate partials [row-half][batch][k]
    __shared__ float red[8];
    __shared__ float wamL[64];          // -2*Wa[s]; [63]=0

    const int tid  = threadIdx.x;
    const int wg   = blockIdx.x;         // 0..255, owns batches 2wg, 2wg+1
    const int n2   = tid & 255;          // n2 for P2/P4; gate-quad for streams
    const int b    = tid >> 8;           // batch for P2/P4
    const int half = tid >> 8;           // input-row half for weight streams
    const int bG   = wg*2 + b;

    // ---- prologue ----
    hcp[b][n2] = 0u;                     // h=c=0
    if (tid < 64) wamL[tid] = (tid < 63) ? (-2.0f * Wa[tid]) : 0.0f;
    if (tid < 128) ((float*)t1s)[tid] = 0.0f;
    float4 bi4 = make_float4(0.f, 0.f, 0.f, 0.f);   // bias once (half 0 only)
    if (half == 0) bi4 = *(const float4*)&biasg[4*n2];
    float bcv = 0.0f;
    if (tid < 126){
        int pb = (tid >= 63) ? 1 : 0;
        bcv = C2 * bc[tid - 63*pb];
    }
    // stage t2 (pre-scaled h2 pairs) into LDS, transposed to [b][n2][s]
    {
        const u32* tg = (const u32*)(t2g + (size_t)bG*63*512);
        u32* trw = &t2l[b][n2][0];
        for (int s = 0; s < 63; ++s) trw[s] = tg[s*256 + n2];
        trw[63] = 0u; trw[64] = 0u; trw[65] = 0u;
    }
    float c_reg = 0.0f;                 // this thread's fp32 cell state (j = n2, batch b)
    // dwordx4 stream bases: column = gate-quad n2, rows = this half's rows.
    const uint4* ihb = (const uint4*)WihP + (size_t)(half*128)*256 + n2;
    const uint4* hhb = (const uint4*)WhhP + (size_t)(half*64)*256 + n2;
    const int HJ = half*64;              // hcp row base for hh consume
    __syncthreads();

    uint4 B0[8], B1[8];

    for (int t = 0; t < 63; ++t){
        // step prologue: x-vector + first 2 W_hh blocks in flight across
        // phase 1 and both lgkm-only barriers.
        float2 xv = *(const float2*)(inp + ((size_t)bG*63 + t)*512 + 2*n2);
        PRE8Q(B0, hhb)
        PRE8Q(B1, hhb + 2048)

        // ---------- phase 1: t1[b][s] = C2*([h|c].Wc[s] + bc[s])  (fp16 dot2)
        if (tid < 504){
            int oi = tid >> 2, sl = tid & 3;
            int pb = (oi >= 63) ? 1 : 0;
            int s  = oi - 63*pb;
            const uint4* xv4 = (const uint4*)&hcp[pb][sl*64];
            const uint4* wv4 = (const uint4*)(WcH + s*512 + sl*128);
            float acc = 0.f;
            #pragma unroll
            for (int i = 0; i < 16; ++i){
                uint4 x = xv4[i], w = wv4[i];
                acc = dot2h(x.x, w.x, acc);
                acc = dot2h(x.y, w.y, acc);
                acc = dot2h(x.z, w.z, acc);
                acc = dot2h(x.w, w.w, acc);
            }
            t1p[oi][sl] = acc;
        }
        bar_lgkm();
        if (tid < 126){
            int pb = (tid >= 63) ? 1 : 0;
            int s  = tid - 63*pb;
            float4 v = *(const float4*)&t1p[tid][0];
            t1s[pb][s] = bcv + v.x + v.y + v.z + v.w;
        }
        bar_lgkm();

        // ---------- phase 2: scores interleaved with the W_hh stream
        //            (8 blocks/thread; W_hh needs only h(t-1) = hcp)
        float acc0 = 0.f, acc1 = 0.f;
        float a0 = bi4.x, a1 = bi4.y, a2 = bi4.z, a3 = bi4.w;
        float b0 = bi4.x, b1 = bi4.y, b2 = bi4.z, b3 = bi4.w;
        const u32*   trow = &t2l[b][n2][0];
        const float* t1r  = &t1s[b][0];
        {
            P2_ITER(0)  P2_ITER(1)
            CONSUME8Q(B0, hcp[0], hcp[1], HJ+0)
            PRE8Q(B0, hhb + 2*2048)
            P2_ITER(2)  P2_ITER(3)
            P2_ITER(4)  P2_ITER(5)
            CONSUME8Q(B1, hcp[0], hcp[1], HJ+8)
            PRE8Q(B1, hhb + 3*2048)
            P2_ITER(6)  P2_ITER(7)
            P2_ITER(8)  P2_ITER(9)
            CONSUME8Q(B0, hcp[0], hcp[1], HJ+16)
            PRE8Q(B0, hhb + 4*2048)
            P2_ITER(10) P2_ITER(11)
            P2_ITER(12) P2_ITER(13)
            CONSUME8Q(B1, hcp[0], hcp[1], HJ+24)
            PRE8Q(B1, hhb + 5*2048)
            P2_ITER(14) P2_ITER(15)
            P2_ITER(16) P2_ITER(17)
            CONSUME8Q(B0, hcp[0], hcp[1], HJ+32)
            PRE8Q(B0, hhb + 6*2048)
            P2_ITER(18) P2_ITER(19)
            P2_ITER(20) P2_ITER(21)
            CONSUME8Q(B1, hcp[0], hcp[1], HJ+40)
            PRE8Q(B1, hhb + 7*2048)
            P2_ITER(22) P2_ITER(23)
            P2_ITER(24) P2_ITER(25)
            CONSUME8Q(B0, hcp[0], hcp[1], HJ+48)
            PRE8Q(B0, ihb)                   // W_ih blocks 0,1 ride across
            P2_ITER(26) P2_ITER(27)          // softmax + 2 barriers
            P2_ITER(28) P2_ITER(29)
            CONSUME8Q(B1, hcp[0], hcp[1], HJ+56)
            PRE8Q(B1, ihb + 2048)
            P2_ITER(30) P2_ITER(31)
        }
        // scores shifted by a batch-constant (dropped Swa) — softmax invariant
        float e0 = exp_fast(acc0);
        float e1 = exp_fast(acc1);
        float es = e0 + e1;
        #pragma unroll
        for (int off = 32; off > 0; off >>= 1) es += __shfl_xor(es, off, 64);
        if ((tid & 63) == 0) red[tid >> 6] = es;
        bar_lgkm();
        float tot  = red[b*4+0] + red[b*4+1] + red[b*4+2] + red[b*4+3];
        float rinv = __builtin_amdgcn_rcpf(tot);
        float at0 = e0*rinv, at1 = e1*rinv;
        float wx0 = at0*xv.x, wx1 = at1*xv.y;
        {
            float2* po = (float2*)(out + ((size_t)bG*63 + t)*512) + n2;
            *po = make_float2(wx0, wx1);
            float2* pa = (float2*)(out + OFF_W + ((size_t)bG*63 + t)*512) + n2;
            *pa = make_float2(at0, at1);
            h2 p; p[0] = (h1)wx0; p[1] = (h1)wx1;
            wxp[b][n2] = __builtin_bit_cast(u32, p);
        }
        bar_lgkm();                          // wxp visible; vmcnt NOT drained

        // ---------- phase 3: gates += wx.W_ih^T (16 blocks/thread, 2-buffer)
        {
            const int J = half*128;
            #pragma unroll 1
            for (int blk = 0; blk < 14; blk += 2){
                CONSUME8Q(B0, wxp[0], wxp[1], J + 8*blk)
                PRE8Q(B0, ihb + (blk+2)*2048)
                CONSUME8Q(B1, wxp[0], wxp[1], J + 8*blk + 8)
                PRE8Q(B1, ihb + (blk+3)*2048)
            }
            CONSUME8Q(B0, wxp[0], wxp[1], J + 112)   // tail pair, no overfetch
            CONSUME8Q(B1, wxp[0], wxp[1], J + 120)
        }
        *(float4*)&gU[half][0][4*n2] = make_float4(a0, a1, a2, a3);
        *(float4*)&gU[half][1][4*n2] = make_float4(b0, b1, b2, b3);
        bar_lgkm();

        // ---------- phase 4: LSTM pointwise (thread: j = n2, batch b)
        {
            int j = n2;
            float gi = gU[0][b][j]     + gU[1][b][j];
            float gf = gU[0][b][j+256] + gU[1][b][j+256];
            float gg = gU[0][b][j+512] + gU[1][b][j+512];
            float go = gU[0][b][j+768] + gU[1][b][j+768];
            float iv = sigmoid_fast(gi), fv = sigmoid_fast(gf);
            float gv = tanh_fast(gg),    ov = sigmoid_fast(go);
            float cn = fmaf(fv, c_reg, iv*gv);
            c_reg = cn;
            float hn = ov * tanh_fast(cn);
            ((h1*)&hcp[b][0])[j]   = (h1)hn;   // h packed (phase 1 + W_hh)
            ((h1*)&hcp[b][128])[j] = (h1)cn;   // c packed (phase 1)
            out[OFF_IE + ((size_t)bG*63 + t)*256 + j] = hn;
        }
        bar_lgkm();
    }
}

extern "C" void kernel_launch(void* const* d_in, const int* in_sizes, int n_in,
                              void* d_out, int out_size, void* d_ws, size_t ws_size,
                              hipStream_t stream)
{
    const float* inp = (const float*)d_in[0];
    const float* Wih = (const float*)d_in[1];
    const float* Whh = (const float*)d_in[2];
    const float* bih = (const float*)d_in[3];
    const float* bhh = (const float*)d_in[4];
    const float* Wc  = (const float*)d_in[5];
    const float* bc  = (const float*)d_in[6];
    const float* Wd  = (const float*)d_in[7];
    const float* bd  = (const float*)d_in[8];
    const float* Wa  = (const float*)d_in[9];
    const float* ba  = (const float*)d_in[10];
    float* out = (float*)d_out;

    char* ws = (char*)d_ws;
    h1*    t2    = (h1*)ws;
    u32*   WihP  = (u32*)(ws + 33030144);
    u32*   WhhP  = (u32*)(ws + 34078720);
    h1*    WcH   = (h1*)(ws + 34603008);
    float* biasg = (float*)(ws + 34667520);

    prep_pack<<<1666, 256, 0, stream>>>(Wih, Whh, bih, bhh, Wc, WihP, WhhP, WcH, biasg);
    prep_t2<<<dim3(512, 2), 256, 0, stream>>>(inp, Wd, bd, t2);
    encoder_main<<<256, 512, 0, stream>>>(inp, bc, Wa, ba, t2, WihP, WhhP, WcH, biasg, out);
}